// Round 1
// baseline (416.775 us; speedup 1.0000x reference)
//
#include <hip/hip_runtime.h>

#define NN 40000
#define NE 640000
#define F 128
#define NC 16
#define NT 32   // nodes per GEMM block

// ws layout (bytes)
#define OFF_ROWPTR 0u
#define OFF_FILL   163840u
#define OFF_SORTED 327680u
#define OFF_STATS  2887680u   // [0:128) sum, [128:256) sumsq, [256:384) bn_a, [384:512) bn_b
#define OFF_WT     2889728u   // 4 transposed 128x128 matrices: W1lT, W1rT, W2lT, W2rT
#define OFF_AGGM   3151872u
#define OFF_RBUF   23631872u

__global__ __launch_bounds__(256) void k_hist(const int* __restrict__ ei, int* __restrict__ hist) {
    int e = blockIdx.x * 256 + threadIdx.x;
    if (e < NE) atomicAdd(&hist[ei[NE + e]], 1);
}

__global__ __launch_bounds__(1024) void k_scan(int* __restrict__ hist, int* __restrict__ rowptr) {
    __shared__ int buf[1024];
    int t = threadIdx.x;
    int base = 0;
    for (int c = 0; c < 40; ++c) {
        int idx = c * 1024 + t;
        int v = (idx < NN) ? hist[idx] : 0;
        buf[t] = v; __syncthreads();
        for (int off = 1; off < 1024; off <<= 1) {
            int x = (t >= off) ? buf[t - off] : 0;
            __syncthreads();
            buf[t] += x; __syncthreads();
        }
        int excl = base + buf[t] - v;
        if (idx < NN) { rowptr[idx] = excl; hist[idx] = excl; }
        base += buf[1023];
        __syncthreads();
    }
    if (t == 0) rowptr[NN] = NE;
}

__global__ __launch_bounds__(256) void k_scatter(const int* __restrict__ ei, int* __restrict__ fill,
                                                 int* __restrict__ sorted) {
    int e = blockIdx.x * 256 + threadIdx.x;
    if (e < NE) {
        int src = ei[e], dst = ei[NE + e];
        int pos = atomicAdd(&fill[dst], 1);
        sorted[pos] = src;
    }
}

__global__ __launch_bounds__(256) void k_transpose(const float* __restrict__ W1l, const float* __restrict__ W1r,
                                                    const float* __restrict__ W2l, const float* __restrict__ W2r,
                                                    float* __restrict__ WT) {
    int i = blockIdx.x * 256 + threadIdx.x;      // < 4*16384
    int m = i >> 14, rc = i & 16383, r = rc >> 7, c = rc & 127;
    const float* src = (m == 0) ? W1l : (m == 1) ? W1r : (m == 2) ? W2l : W2r;
    WT[m * 16384 + c * 128 + r] = src[rc];
}

template<int CONV2>
__global__ __launch_bounds__(256) void k_agg(const float* __restrict__ feat, const int* __restrict__ rowptr,
                                             const int* __restrict__ sorted, const float* __restrict__ bn_a,
                                             const float* __restrict__ bn_b, float* __restrict__ aggm) {
    int node = (blockIdx.x << 2) + (threadIdx.x >> 6);
    int lane = threadIdx.x & 63;
    int e0 = rowptr[node], e1 = rowptr[node + 1];
    int f = lane << 1;
    float ax = 0.f, ay = 0.f;
    for (int e = e0; e < e1; ++e) {
        int s = sorted[e];
        float2 v = *(const float2*)&feat[(size_t)s * F + f];
        ax += v.x; ay += v.y;
    }
    int cnt = e1 - e0;
    float inv = 1.f / (float)(cnt > 1 ? cnt : 1);
    ax *= inv; ay *= inv;
    if constexpr (CONV2) {
        if (cnt > 0) {
            ax = fmaf(bn_a[f], ax, bn_b[f]);
            ay = fmaf(bn_a[f + 1], ay, bn_b[f + 1]);
        }   // cnt==0 -> agg stays 0 (matches segment_sum semantics)
    }
    float2 o; o.x = ax; o.y = ay;
    *(float2*)&aggm[(size_t)node * F + f] = o;
}

__global__ __launch_bounds__(128) void k_bnfinal(float* __restrict__ stats, const float* __restrict__ gamma,
                                                 const float* __restrict__ beta) {
    int t = threadIdx.x;
    float mu  = stats[t] * (1.f / NN);
    float var = stats[F + t] * (1.f / NN) - mu * mu;
    float a = gamma[t] * rsqrtf(var + 1e-5f);
    stats[256 + t] = a;
    stats[384 + t] = beta[t] - mu * a;
}

#define FMA4(AR, W, S) \
    AR[0] = fmaf((W).x, (S), AR[0]); \
    AR[1] = fmaf((W).y, (S), AR[1]); \
    AR[2] = fmaf((W).z, (S), AR[2]); \
    AR[3] = fmaf((W).w, (S), AR[3]);

template<int CONV2>
__global__ __launch_bounds__(256) void k_gemm(
    const float* __restrict__ aggm, const float* __restrict__ xg,
    const float* __restrict__ WlT, const float* __restrict__ WrT,
    const float* __restrict__ bias,
    const float* __restrict__ bn_a, const float* __restrict__ bn_b,
    float* __restrict__ rbuf, float* __restrict__ stats,
    const float* __restrict__ Wfc, const float* __restrict__ bfc,
    float* __restrict__ out)
{
    __shared__ float sA[NT][F];
    __shared__ float sX[NT][F];
    __shared__ float scale[NT];
    int t = threadIdx.x;
    int nb = blockIdx.x * NT;

    // stage input tiles (row-major, coalesced float4 loads; conv2 folds BN affine into self rows)
    for (int i = t; i < NT * F / 4; i += 256) {
        int n = i >> 5;
        int k4 = (i & 31) << 2;
        float4 va = *(const float4*)&aggm[(size_t)(nb + n) * F + k4];
        float4 vx = *(const float4*)&xg[(size_t)(nb + n) * F + k4];
        if constexpr (CONV2) {
            float4 a4 = *(const float4*)&bn_a[k4];
            float4 b4 = *(const float4*)&bn_b[k4];
            vx.x = fmaf(a4.x, vx.x, b4.x);
            vx.y = fmaf(a4.y, vx.y, b4.y);
            vx.z = fmaf(a4.z, vx.z, b4.z);
            vx.w = fmaf(a4.w, vx.w, b4.w);
        }
        *(float4*)&sA[n][k4] = va;
        *(float4*)&sX[n][k4] = vx;
    }
    __syncthreads();

    int tn = (t >> 5) << 2;   // node base (0..28)
    int to = (t & 31) << 2;   // out base  (0..124)
    float acc[4][4];
    #pragma unroll
    for (int i = 0; i < 4; ++i)
        #pragma unroll
        for (int j = 0; j < 4; ++j) acc[i][j] = 0.f;

    for (int k = 0; k < F; k += 4) {
        float4 wl[4], wr[4];
        #pragma unroll
        for (int j = 0; j < 4; ++j) {
            wl[j] = *(const float4*)&WlT[(k + j) * F + to];
            wr[j] = *(const float4*)&WrT[(k + j) * F + to];
        }
        #pragma unroll
        for (int ni = 0; ni < 4; ++ni) {
            float4 av = *(const float4*)&sA[tn + ni][k];
            float4 xv = *(const float4*)&sX[tn + ni][k];
            float* ar = acc[ni];
            FMA4(ar, wl[0], av.x) FMA4(ar, wl[1], av.y) FMA4(ar, wl[2], av.z) FMA4(ar, wl[3], av.w)
            FMA4(ar, wr[0], xv.x) FMA4(ar, wr[1], xv.y) FMA4(ar, wr[2], xv.z) FMA4(ar, wr[3], xv.w)
        }
    }

    // bias
    float4 bv = *(const float4*)&bias[to];
    #pragma unroll
    for (int ni = 0; ni < 4; ++ni) {
        acc[ni][0] += bv.x; acc[ni][1] += bv.y; acc[ni][2] += bv.z; acc[ni][3] += bv.w;
    }

    // row L2 norm: shuffle-reduce sum of squares across the 32 lanes sharing each node group
    #pragma unroll
    for (int ni = 0; ni < 4; ++ni) {
        float s = acc[ni][0] * acc[ni][0] + acc[ni][1] * acc[ni][1]
                + acc[ni][2] * acc[ni][2] + acc[ni][3] * acc[ni][3];
        #pragma unroll
        for (int off = 1; off <= 16; off <<= 1) s += __shfl_xor(s, off);
        if ((t & 31) == 0) scale[tn + ni] = 1.f / fmaxf(sqrtf(s), 1e-12f);
    }
    __syncthreads();   // k-loop reads of sA/sX done in all waves; scale visible

    if constexpr (!CONV2) {
        // normalize + relu; store to rbuf and stash in sA (reused as hout) for BN stats
        #pragma unroll
        for (int ni = 0; ni < 4; ++ni) {
            float sc = scale[tn + ni];
            float4 v;
            v.x = fmaxf(acc[ni][0] * sc, 0.f);
            v.y = fmaxf(acc[ni][1] * sc, 0.f);
            v.z = fmaxf(acc[ni][2] * sc, 0.f);
            v.w = fmaxf(acc[ni][3] * sc, 0.f);
            *(float4*)&sA[tn + ni][to] = v;
            *(float4*)&rbuf[(size_t)(nb + tn + ni) * F + to] = v;
        }
        __syncthreads();
        if (t < F) {
            float s = 0.f, s2 = 0.f;
            #pragma unroll
            for (int r = 0; r < NT; ++r) {
                float v = sA[r][t];
                s += v; s2 += v * v;
            }
            atomicAdd(&stats[t], s);
            atomicAdd(&stats[F + t], s2);
        }
    } else {
        // normalize -> h3 in sA; then fused fc -> out
        #pragma unroll
        for (int ni = 0; ni < 4; ++ni) {
            float sc = scale[tn + ni];
            float4 v;
            v.x = acc[ni][0] * sc; v.y = acc[ni][1] * sc;
            v.z = acc[ni][2] * sc; v.w = acc[ni][3] * sc;
            *(float4*)&sA[tn + ni][to] = v;
        }
        __syncthreads();
        for (int p = t; p < NT * NC; p += 256) {
            int n = p >> 4, c = p & 15;
            float s = bfc[c];
            for (int o = 0; o < F; o += 4) {
                float4 h4 = *(const float4*)&sA[n][o];
                float4 w4 = *(const float4*)&Wfc[c * F + o];
                s += h4.x * w4.x + h4.y * w4.y + h4.z * w4.z + h4.w * w4.w;
            }
            out[(size_t)(nb + n) * NC + c] = s;
        }
    }
}

extern "C" void kernel_launch(void* const* d_in, const int* in_sizes, int n_in,
                              void* d_out, int out_size, void* d_ws, size_t ws_size,
                              hipStream_t stream) {
    const float* x     = (const float*)d_in[0];
    const int*   ei    = (const int*)d_in[1];
    const float* W1l   = (const float*)d_in[2];
    const float* b1l   = (const float*)d_in[3];
    const float* W1r   = (const float*)d_in[4];
    const float* gamma = (const float*)d_in[5];
    const float* beta  = (const float*)d_in[6];
    const float* W2l   = (const float*)d_in[7];
    const float* b2l   = (const float*)d_in[8];
    const float* W2r   = (const float*)d_in[9];
    const float* Wfc   = (const float*)d_in[10];
    const float* bfc   = (const float*)d_in[11];

    char* ws = (char*)d_ws;
    int*   rowptr = (int*)(ws + OFF_ROWPTR);
    int*   fill   = (int*)(ws + OFF_FILL);
    int*   sorted = (int*)(ws + OFF_SORTED);
    float* stats  = (float*)(ws + OFF_STATS);
    float* WT     = (float*)(ws + OFF_WT);
    float* aggm   = (float*)(ws + OFF_AGGM);
    float* rbuf   = (float*)(ws + OFF_RBUF);
    float* out    = (float*)d_out;

    hipMemsetAsync(fill, 0, NN * sizeof(int), stream);
    hipMemsetAsync(stats, 0, 256 * sizeof(float), stream);

    k_transpose<<<256, 256, 0, stream>>>(W1l, W1r, W2l, W2r, WT);
    k_hist<<<(NE + 255) / 256, 256, 0, stream>>>(ei, fill);
    k_scan<<<1, 1024, 0, stream>>>(fill, rowptr);
    k_scatter<<<(NE + 255) / 256, 256, 0, stream>>>(ei, fill, sorted);

    // conv1
    k_agg<0><<<NN / 4, 256, 0, stream>>>(x, rowptr, sorted, nullptr, nullptr, aggm);
    k_gemm<0><<<NN / NT, 256, 0, stream>>>(aggm, x, WT, WT + 16384, b1l,
                                           nullptr, nullptr, rbuf, stats,
                                           nullptr, nullptr, nullptr);
    k_bnfinal<<<1, 128, 0, stream>>>(stats, gamma, beta);

    // conv2 (+ fused fc)
    k_agg<1><<<NN / 4, 256, 0, stream>>>(rbuf, rowptr, sorted, stats + 256, stats + 384, aggm);
    k_gemm<1><<<NN / NT, 256, 0, stream>>>(aggm, rbuf, WT + 32768, WT + 49152, b2l,
                                           stats + 256, stats + 384, nullptr, nullptr,
                                           Wfc, bfc, out);
}

// Round 3
// 378.513 us; speedup vs baseline: 1.1011x; 1.1011x over previous
//
#include <hip/hip_runtime.h>

#define NN 40000
#define NE 640000
#define F 128
#define NC 16
#define NT 32   // nodes per GEMM block

// ws layout (bytes) — NOTE: stats region is 2048 B (sum/sumsq/bn_a/bn_b × 128 floats).
// Round-2 bug: OFF_WT overlapped stats[128..] so conv1's sumsq atomics stomped W1lT. Keep gap = 2048.
#define OFF_ROWPTR 0u          // (NN+1) ints              -> 160004
#define OFF_FILL   163968u     // NN ints                  -> 323968
#define OFF_BSUM   327936u     // 64 ints                  -> 328192
#define OFF_SORTED 328192u     // NE ints                  -> 2888192
#define OFF_STATS  2888192u    // 512 floats (2048 B)      -> 2890240
#define OFF_WT     2890240u    // 4x 128x128 f32 transposed-> 3152384
#define OFF_RBUF   3152384u    // NN*F floats              -> 23632384

__global__ __launch_bounds__(256) void k_hist(const int* __restrict__ ei, int* __restrict__ cnt) {
    int e = blockIdx.x * 256 + threadIdx.x;
    if (e < NE) atomicAdd(&cnt[ei[NE + e]], 1);
}

// per-block exclusive scan of 1024 counts; writes local-exclusive to rowptr, block total to bsum
__global__ __launch_bounds__(1024) void k_scan1(const int* __restrict__ cnt, int* __restrict__ rowptr,
                                                int* __restrict__ bsum) {
    __shared__ int wsum[16];
    int t = threadIdx.x, b = blockIdx.x;
    int idx = b * 1024 + t;
    int v = (idx < NN) ? cnt[idx] : 0;
    int lane = t & 63, w = t >> 6;
    int val = v;
    #pragma unroll
    for (int off = 1; off < 64; off <<= 1) { int u = __shfl_up(val, off); if (lane >= off) val += u; }
    if (lane == 63) wsum[w] = val;
    __syncthreads();
    if (w == 0) {
        int x = (lane < 16) ? wsum[lane] : 0;
        #pragma unroll
        for (int off = 1; off < 16; off <<= 1) { int u = __shfl_up(x, off); if (lane >= off) x += u; }
        if (lane < 16) wsum[lane] = x;
    }
    __syncthreads();
    int excl = val - v + (w > 0 ? wsum[w - 1] : 0);
    if (idx < NN) rowptr[idx] = excl;
    if (t == 1023) bsum[b] = wsum[15];
}

// single wave: exclusive-scan the 40 block sums in place; also set rowptr[NN]
__global__ __launch_bounds__(64) void k_scan2(int* __restrict__ bsum, int* __restrict__ rowptr) {
    int lane = threadIdx.x;
    int v = (lane < 40) ? bsum[lane] : 0;
    int val = v;
    #pragma unroll
    for (int off = 1; off < 64; off <<= 1) { int u = __shfl_up(val, off); if (lane >= off) val += u; }
    if (lane < 40) bsum[lane] = val - v;
    if (lane == 0) rowptr[NN] = NE;
}

__global__ __launch_bounds__(1024) void k_scan3(int* __restrict__ rowptr, const int* __restrict__ bsum,
                                                int* __restrict__ fill) {
    int t = threadIdx.x, b = blockIdx.x;
    int idx = b * 1024 + t;
    if (idx < NN) {
        int r = rowptr[idx] + bsum[b];
        rowptr[idx] = r;
        fill[idx] = r;
    }
}

__global__ __launch_bounds__(256) void k_scatter(const int* __restrict__ ei, int* __restrict__ fill,
                                                 int* __restrict__ sorted) {
    int e = blockIdx.x * 256 + threadIdx.x;
    if (e < NE) {
        int src = ei[e], dst = ei[NE + e];
        int pos = atomicAdd(&fill[dst], 1);
        sorted[pos] = src;
    }
}

__global__ __launch_bounds__(256) void k_transpose(const float* __restrict__ W1l, const float* __restrict__ W1r,
                                                    const float* __restrict__ W2l, const float* __restrict__ W2r,
                                                    float* __restrict__ WT) {
    int i = blockIdx.x * 256 + threadIdx.x;      // < 4*16384
    int m = i >> 14, rc = i & 16383, r = rc >> 7, c = rc & 127;
    const float* src = (m == 0) ? W1l : (m == 1) ? W1r : (m == 2) ? W2l : W2r;
    WT[m * 16384 + c * 128 + r] = src[rc];
}

__global__ __launch_bounds__(128) void k_bnfinal(float* __restrict__ stats, const float* __restrict__ gamma,
                                                 const float* __restrict__ beta) {
    int t = threadIdx.x;
    float mu  = stats[t] * (1.f / NN);
    float var = stats[F + t] * (1.f / NN) - mu * mu;
    float a = gamma[t] * rsqrtf(var + 1e-5f);
    stats[256 + t] = a;
    stats[384 + t] = beta[t] - mu * a;
}

#define FMA4(AR, W, S) \
    AR[0] = fmaf((W).x, (S), AR[0]); \
    AR[1] = fmaf((W).y, (S), AR[1]); \
    AR[2] = fmaf((W).z, (S), AR[2]); \
    AR[3] = fmaf((W).w, (S), AR[3]);

#define KSTEP(CUR) \
    { \
        _Pragma("unroll") \
        for (int ni = 0; ni < 4; ++ni) { \
            float4 av = *(const float4*)&sA[tn + ni][k]; \
            float4 xv = *(const float4*)&sX[tn + ni][k]; \
            float* ar = acc[ni]; \
            FMA4(ar, wl[CUR][0], av.x) FMA4(ar, wl[CUR][1], av.y) \
            FMA4(ar, wl[CUR][2], av.z) FMA4(ar, wl[CUR][3], av.w) \
            FMA4(ar, wr[CUR][0], xv.x) FMA4(ar, wr[CUR][1], xv.y) \
            FMA4(ar, wr[CUR][2], xv.z) FMA4(ar, wr[CUR][3], xv.w) \
        } \
    }

#define WLOAD(BUF, KK) \
    { \
        _Pragma("unroll") \
        for (int j = 0; j < 4; ++j) { \
            wl[BUF][j] = *(const float4*)&WlT[(KK + j) * F + to]; \
            wr[BUF][j] = *(const float4*)&WrT[(KK + j) * F + to]; \
        } \
    }

// Fused: neighbor-mean gather (CSR) + dual GEMM (+bias) + row-L2-norm + epilogue
template<int CONV2>
__global__ __launch_bounds__(256) void k_gemm(
    const float* __restrict__ feat, const int* __restrict__ rowptr, const int* __restrict__ sorted,
    const float* __restrict__ WlT, const float* __restrict__ WrT,
    const float* __restrict__ bias,
    const float* __restrict__ bn_a, const float* __restrict__ bn_b,
    float* __restrict__ rbuf, float* __restrict__ stats,
    const float* __restrict__ Wfc, const float* __restrict__ bfc,
    float* __restrict__ out)
{
    __shared__ float sA[NT][F];   // gathered neighbor means (+BN affine for conv2)
    __shared__ float sX[NT][F];   // self features (+BN affine for conv2)
    __shared__ float scale[NT];
    int t = threadIdx.x;
    int nb = blockIdx.x * NT;

    // ---- stage self rows (coalesced float4; conv2 folds BN affine) ----
    #pragma unroll
    for (int it = 0; it < 4; ++it) {
        int i = t + it * 256;               // i in [0, 1024): n = i>>5, k4 = (i&31)<<2
        int n = i >> 5;
        int k4 = (i & 31) << 2;
        float4 vx = *(const float4*)&feat[(size_t)(nb + n) * F + k4];
        if constexpr (CONV2) {
            float4 a4 = *(const float4*)&bn_a[k4];
            float4 b4 = *(const float4*)&bn_b[k4];
            vx.x = fmaf(a4.x, vx.x, b4.x);
            vx.y = fmaf(a4.y, vx.y, b4.y);
            vx.z = fmaf(a4.z, vx.z, b4.z);
            vx.w = fmaf(a4.w, vx.w, b4.w);
        }
        *(float4*)&sX[n][k4] = vx;
    }

    // ---- gather neighbor means: wave w handles nodes w*8 .. w*8+7, lane owns feature pair ----
    {
        int w = t >> 6, lane = t & 63;
        int f2 = lane << 1;
        float a0 = 0.f, a1 = 0.f, bb0 = 0.f, bb1 = 0.f;
        if constexpr (CONV2) {
            float2 a2 = *(const float2*)&bn_a[f2];
            float2 b2 = *(const float2*)&bn_b[f2];
            a0 = a2.x; a1 = a2.y; bb0 = b2.x; bb1 = b2.y;
        }
        #pragma unroll
        for (int i = 0; i < 8; ++i) {
            int node = nb + w * 8 + i;
            int e0 = rowptr[node], e1 = rowptr[node + 1];
            float ax = 0.f, ay = 0.f;
            int e = e0;
            for (; e + 1 < e1; e += 2) {
                int s0 = sorted[e], s1 = sorted[e + 1];
                float2 v0 = *(const float2*)&feat[(size_t)s0 * F + f2];
                float2 v1 = *(const float2*)&feat[(size_t)s1 * F + f2];
                ax += v0.x + v1.x; ay += v0.y + v1.y;
            }
            if (e < e1) {
                int s0 = sorted[e];
                float2 v0 = *(const float2*)&feat[(size_t)s0 * F + f2];
                ax += v0.x; ay += v0.y;
            }
            int cntn = e1 - e0;
            float inv = 1.f / (float)(cntn > 1 ? cntn : 1);
            ax *= inv; ay *= inv;
            if constexpr (CONV2) {
                if (cntn > 0) { ax = fmaf(a0, ax, bb0); ay = fmaf(a1, ay, bb1); }
            }
            sA[w * 8 + i][f2] = ax;
            sA[w * 8 + i][f2 + 1] = ay;
        }
    }
    __syncthreads();

    // ---- dual GEMM with 2-deep weight register double-buffer ----
    int tn = (t >> 5) << 2;   // node base (0..28)
    int to = (t & 31) << 2;   // out base  (0..124)
    float acc[4][4];
    #pragma unroll
    for (int i = 0; i < 4; ++i)
        #pragma unroll
        for (int j = 0; j < 4; ++j) acc[i][j] = 0.f;

    float4 wl[2][4], wr[2][4];
    WLOAD(0, 0)
    for (int k = 0; k < F - 8; k += 8) {
        WLOAD(1, (k + 4))
        KSTEP(0)
        k += 4;
        WLOAD(0, (k + 4))
        KSTEP(1)
        k -= 4;
    }
    {
        int k = F - 8;
        WLOAD(1, (k + 4))
        KSTEP(0)
        k += 4;
        KSTEP(1)
    }

    // bias
    float4 bv = *(const float4*)&bias[to];
    #pragma unroll
    for (int ni = 0; ni < 4; ++ni) {
        acc[ni][0] += bv.x; acc[ni][1] += bv.y; acc[ni][2] += bv.z; acc[ni][3] += bv.w;
    }

    // row L2 norm: shuffle-reduce across the 32 lanes sharing each node group
    #pragma unroll
    for (int ni = 0; ni < 4; ++ni) {
        float s = acc[ni][0] * acc[ni][0] + acc[ni][1] * acc[ni][1]
                + acc[ni][2] * acc[ni][2] + acc[ni][3] * acc[ni][3];
        #pragma unroll
        for (int off = 1; off <= 16; off <<= 1) s += __shfl_xor(s, off);
        if ((t & 31) == 0) scale[tn + ni] = 1.f / fmaxf(sqrtf(s), 1e-12f);
    }
    __syncthreads();

    if constexpr (!CONV2) {
        // normalize + relu; store to rbuf and stash in sA for BN stats
        #pragma unroll
        for (int ni = 0; ni < 4; ++ni) {
            float sc = scale[tn + ni];
            float4 v;
            v.x = fmaxf(acc[ni][0] * sc, 0.f);
            v.y = fmaxf(acc[ni][1] * sc, 0.f);
            v.z = fmaxf(acc[ni][2] * sc, 0.f);
            v.w = fmaxf(acc[ni][3] * sc, 0.f);
            *(float4*)&sA[tn + ni][to] = v;
            *(float4*)&rbuf[(size_t)(nb + tn + ni) * F + to] = v;
        }
        __syncthreads();
        if (t < F) {
            float s = 0.f, s2 = 0.f;
            #pragma unroll
            for (int r = 0; r < NT; ++r) {
                float v = sA[r][t];
                s += v; s2 += v * v;
            }
            atomicAdd(&stats[t], s);
            atomicAdd(&stats[F + t], s2);
        }
    } else {
        // normalize -> h3 in sA; then fused fc -> out
        #pragma unroll
        for (int ni = 0; ni < 4; ++ni) {
            float sc = scale[tn + ni];
            float4 v;
            v.x = acc[ni][0] * sc; v.y = acc[ni][1] * sc;
            v.z = acc[ni][2] * sc; v.w = acc[ni][3] * sc;
            *(float4*)&sA[tn + ni][to] = v;
        }
        __syncthreads();
        for (int p = t; p < NT * NC; p += 256) {
            int n = p >> 4, c = p & 15;
            float s = bfc[c];
            for (int o = 0; o < F; o += 4) {
                float4 h4 = *(const float4*)&sA[n][o];
                float4 w4 = *(const float4*)&Wfc[c * F + o];
                s += h4.x * w4.x + h4.y * w4.y + h4.z * w4.z + h4.w * w4.w;
            }
            out[(size_t)(nb + n) * NC + c] = s;
        }
    }
}

extern "C" void kernel_launch(void* const* d_in, const int* in_sizes, int n_in,
                              void* d_out, int out_size, void* d_ws, size_t ws_size,
                              hipStream_t stream) {
    const float* x     = (const float*)d_in[0];
    const int*   ei    = (const int*)d_in[1];
    const float* W1l   = (const float*)d_in[2];
    const float* b1l   = (const float*)d_in[3];
    const float* W1r   = (const float*)d_in[4];
    const float* gamma = (const float*)d_in[5];
    const float* beta  = (const float*)d_in[6];
    const float* W2l   = (const float*)d_in[7];
    const float* b2l   = (const float*)d_in[8];
    const float* W2r   = (const float*)d_in[9];
    const float* Wfc   = (const float*)d_in[10];
    const float* bfc   = (const float*)d_in[11];

    char* ws = (char*)d_ws;
    int*   rowptr = (int*)(ws + OFF_ROWPTR);
    int*   fill   = (int*)(ws + OFF_FILL);
    int*   bsum   = (int*)(ws + OFF_BSUM);
    int*   sorted = (int*)(ws + OFF_SORTED);
    float* stats  = (float*)(ws + OFF_STATS);
    float* WT     = (float*)(ws + OFF_WT);
    float* rbuf   = (float*)(ws + OFF_RBUF);
    float* out    = (float*)d_out;

    hipMemsetAsync(fill, 0, NN * sizeof(int), stream);
    hipMemsetAsync(stats, 0, 256 * sizeof(float), stream);

    k_transpose<<<256, 256, 0, stream>>>(W1l, W1r, W2l, W2r, WT);
    k_hist<<<(NE + 255) / 256, 256, 0, stream>>>(ei, fill);
    k_scan1<<<40, 1024, 0, stream>>>(fill, rowptr, bsum);
    k_scan2<<<1, 64, 0, stream>>>(bsum, rowptr);
    k_scan3<<<40, 1024, 0, stream>>>(rowptr, bsum, fill);
    k_scatter<<<(NE + 255) / 256, 256, 0, stream>>>(ei, fill, sorted);

    // conv1 (fused gather + dual GEMM + L2norm + ReLU + BN partial stats)
    k_gemm<0><<<NN / NT, 256, 0, stream>>>(x, rowptr, sorted, WT, WT + 16384, b1l,
                                           nullptr, nullptr, rbuf, stats,
                                           nullptr, nullptr, nullptr);
    k_bnfinal<<<1, 128, 0, stream>>>(stats, gamma, beta);

    // conv2 (fused BN-fold + gather + dual GEMM + L2norm + fc)
    k_gemm<1><<<NN / NT, 256, 0, stream>>>(rbuf, rowptr, sorted, WT + 32768, WT + 49152, b2l,
                                           stats + 256, stats + 384, nullptr, nullptr,
                                           Wfc, bfc, out);
}

// Round 4
// 270.816 us; speedup vs baseline: 1.5390x; 1.3977x over previous
//
#include <hip/hip_runtime.h>

#define NN 40000
#define NE 640000
#define F 128
#define NC 16
#define NT 32   // nodes per GEMM block

// ws layout (bytes). stats region is 2048 B (sum/sumsq/bn_a/bn_b x 128 f32) — round-2 bug was
// shrinking this; keep the gap. Total footprint 23632384 B == round-1 proven-good size.
#define OFF_ROWPTR 0u          // (NN+1) ints              -> 160004
#define OFF_FILL   163968u     // NN ints                  -> 323968
#define OFF_BSUM   327936u     // 64 ints                  -> 328192
#define OFF_SORTED 328192u     // NE ints                  -> 2888192
#define OFF_STATS  2888192u    // 512 floats (2048 B)      -> 2890240
#define OFF_WT     2890240u    // 4x 128x128 f32 transposed-> 3152384
#define OFF_RBH    3152384u    // NN*F bf16 (h1)           -> 13392384
#define OFF_AGGM   13392384u   // NN*F bf16 (agg, reused conv1 then conv2) -> 23632384

__device__ __forceinline__ unsigned short f2b(float f) {   // f32 -> bf16 RNE
    unsigned u = __builtin_bit_cast(unsigned, f);
    return (unsigned short)((u + 0x7fffu + ((u >> 16) & 1u)) >> 16);
}
__device__ __forceinline__ float b2f(unsigned short s) {
    return __builtin_bit_cast(float, (unsigned)s << 16);
}

__global__ __launch_bounds__(256) void k_hist(const int* __restrict__ ei, int* __restrict__ cnt) {
    int e = blockIdx.x * 256 + threadIdx.x;
    if (e < NE) atomicAdd(&cnt[ei[NE + e]], 1);
}

__global__ __launch_bounds__(1024) void k_scan1(const int* __restrict__ cnt, int* __restrict__ rowptr,
                                                int* __restrict__ bsum) {
    __shared__ int wsum[16];
    int t = threadIdx.x, b = blockIdx.x;
    int idx = b * 1024 + t;
    int v = (idx < NN) ? cnt[idx] : 0;
    int lane = t & 63, w = t >> 6;
    int val = v;
    #pragma unroll
    for (int off = 1; off < 64; off <<= 1) { int u = __shfl_up(val, off); if (lane >= off) val += u; }
    if (lane == 63) wsum[w] = val;
    __syncthreads();
    if (w == 0) {
        int x = (lane < 16) ? wsum[lane] : 0;
        #pragma unroll
        for (int off = 1; off < 16; off <<= 1) { int u = __shfl_up(x, off); if (lane >= off) x += u; }
        if (lane < 16) wsum[lane] = x;
    }
    __syncthreads();
    int excl = val - v + (w > 0 ? wsum[w - 1] : 0);
    if (idx < NN) rowptr[idx] = excl;
    if (t == 1023) bsum[b] = wsum[15];
}

__global__ __launch_bounds__(64) void k_scan2(int* __restrict__ bsum, int* __restrict__ rowptr) {
    int lane = threadIdx.x;
    int v = (lane < 40) ? bsum[lane] : 0;
    int val = v;
    #pragma unroll
    for (int off = 1; off < 64; off <<= 1) { int u = __shfl_up(val, off); if (lane >= off) val += u; }
    if (lane < 40) bsum[lane] = val - v;
    if (lane == 0) rowptr[NN] = NE;
}

__global__ __launch_bounds__(1024) void k_scan3(int* __restrict__ rowptr, const int* __restrict__ bsum,
                                                int* __restrict__ fill) {
    int t = threadIdx.x, b = blockIdx.x;
    int idx = b * 1024 + t;
    if (idx < NN) {
        int r = rowptr[idx] + bsum[b];
        rowptr[idx] = r;
        fill[idx] = r;
    }
}

__global__ __launch_bounds__(256) void k_scatter(const int* __restrict__ ei, int* __restrict__ fill,
                                                 int* __restrict__ sorted) {
    int e = blockIdx.x * 256 + threadIdx.x;
    if (e < NE) {
        int src = ei[e], dst = ei[NE + e];
        int pos = atomicAdd(&fill[dst], 1);
        sorted[pos] = src;
    }
}

__global__ __launch_bounds__(256) void k_transpose(const float* __restrict__ W1l, const float* __restrict__ W1r,
                                                    const float* __restrict__ W2l, const float* __restrict__ W2r,
                                                    float* __restrict__ WT) {
    int i = blockIdx.x * 256 + threadIdx.x;      // < 4*16384
    int m = i >> 14, rc = i & 16383, r = rc >> 7, c = rc & 127;
    const float* src = (m == 0) ? W1l : (m == 1) ? W1r : (m == 2) ? W2l : W2r;
    WT[m * 16384 + c * 128 + r] = src[rc];
}

__global__ __launch_bounds__(128) void k_bnfinal(float* __restrict__ stats, const float* __restrict__ gamma,
                                                 const float* __restrict__ beta) {
    int t = threadIdx.x;
    float mu  = stats[t] * (1.f / NN);
    float var = stats[F + t] * (1.f / NN) - mu * mu;
    float a = gamma[t] * rsqrtf(var + 1e-5f);
    stats[256 + t] = a;
    stats[384 + t] = beta[t] - mu * a;
}

// Gather: one wave per node; lane halves cover 2 edges concurrently (4-elem chunks per lane),
// unrolled x4 -> 8 row-loads in flight per wave. No LDS -> full occupancy (32 waves/CU).
template<int CONV2>
__global__ __launch_bounds__(256) void k_agg(
    const float* __restrict__ featf,            // conv1: f32 feature rows
    const unsigned short* __restrict__ featb,   // conv2: bf16 feature rows
    const int* __restrict__ rowptr, const int* __restrict__ sorted,
    const float* __restrict__ bn_a, const float* __restrict__ bn_b,
    unsigned short* __restrict__ aggm)
{
    int node = (blockIdx.x << 2) + (threadIdx.x >> 6);
    int lane = threadIdx.x & 63;
    int half = lane >> 5, li = lane & 31;
    int f4 = li << 2;
    int e0 = rowptr[node], e1 = rowptr[node + 1];
    int deg = e1 - e0;
    float a0 = 0.f, a1 = 0.f, a2 = 0.f, a3 = 0.f;

#define ACC_EDGE(SRC) do { \
        if constexpr (CONV2) { \
            ushort4 u = *(const ushort4*)&featb[(size_t)(SRC) * F + f4]; \
            a0 += b2f(u.x); a1 += b2f(u.y); a2 += b2f(u.z); a3 += b2f(u.w); \
        } else { \
            float4 v = *(const float4*)&featf[(size_t)(SRC) * F + f4]; \
            a0 += v.x; a1 += v.y; a2 += v.z; a3 += v.w; \
        } } while (0)

    int e = e0;
    for (; e + 8 <= e1; e += 8) {
        int s0 = sorted[e + half];
        int s1 = sorted[e + 2 + half];
        int s2 = sorted[e + 4 + half];
        int s3 = sorted[e + 6 + half];
        ACC_EDGE(s0); ACC_EDGE(s1); ACC_EDGE(s2); ACC_EDGE(s3);
    }
    for (; e + 2 <= e1; e += 2) {
        int s0 = sorted[e + half];
        ACC_EDGE(s0);
    }
    if (e < e1 && half == 0) {
        int s0 = sorted[e];
        ACC_EDGE(s0);
    }
#undef ACC_EDGE

    a0 += __shfl_xor(a0, 32);
    a1 += __shfl_xor(a1, 32);
    a2 += __shfl_xor(a2, 32);
    a3 += __shfl_xor(a3, 32);

    if (half == 0) {
        float inv = 1.f / (float)(deg > 1 ? deg : 1);
        a0 *= inv; a1 *= inv; a2 *= inv; a3 *= inv;
        if constexpr (CONV2) {
            if (deg > 0) {
                a0 = fmaf(bn_a[f4],     a0, bn_b[f4]);
                a1 = fmaf(bn_a[f4 + 1], a1, bn_b[f4 + 1]);
                a2 = fmaf(bn_a[f4 + 2], a2, bn_b[f4 + 2]);
                a3 = fmaf(bn_a[f4 + 3], a3, bn_b[f4 + 3]);
            }
        }
        ushort4 o;
        o.x = f2b(a0); o.y = f2b(a1); o.z = f2b(a2); o.w = f2b(a3);
        *(ushort4*)&aggm[(size_t)node * F + f4] = o;
    }
}

#define FMA4(AR, W, S) \
    AR[0] = fmaf((W).x, (S), AR[0]); \
    AR[1] = fmaf((W).y, (S), AR[1]); \
    AR[2] = fmaf((W).z, (S), AR[2]); \
    AR[3] = fmaf((W).w, (S), AR[3]);

#define KSTEP(CUR) \
    { \
        _Pragma("unroll") \
        for (int ni = 0; ni < 4; ++ni) { \
            float4 av = *(const float4*)&sA[tn + ni][k]; \
            float4 xv = *(const float4*)&sX[tn + ni][k]; \
            float* ar = acc[ni]; \
            FMA4(ar, wl[CUR][0], av.x) FMA4(ar, wl[CUR][1], av.y) \
            FMA4(ar, wl[CUR][2], av.z) FMA4(ar, wl[CUR][3], av.w) \
            FMA4(ar, wr[CUR][0], xv.x) FMA4(ar, wr[CUR][1], xv.y) \
            FMA4(ar, wr[CUR][2], xv.z) FMA4(ar, wr[CUR][3], xv.w) \
        } \
    }

#define WLOAD(BUF, KK) \
    { \
        _Pragma("unroll") \
        for (int j = 0; j < 4; ++j) { \
            wl[BUF][j] = *(const float4*)&WlT[(KK + j) * F + to]; \
            wr[BUF][j] = *(const float4*)&WrT[(KK + j) * F + to]; \
        } \
    }

// Dual GEMM (+bias) + row-L2-norm + epilogue. sA from bf16 aggm; sX self path.
template<int CONV2>
__global__ __launch_bounds__(256) void k_gemm(
    const unsigned short* __restrict__ aggm,
    const float* __restrict__ xf,               // conv1 self rows (f32)
    const unsigned short* __restrict__ xb,      // conv2 self rows (bf16 h1)
    const float* __restrict__ WlT, const float* __restrict__ WrT,
    const float* __restrict__ bias,
    const float* __restrict__ bn_a, const float* __restrict__ bn_b,
    unsigned short* __restrict__ rbh, float* __restrict__ stats,
    const float* __restrict__ Wfc, const float* __restrict__ bfc,
    float* __restrict__ out)
{
    __shared__ float sA[NT][F];
    __shared__ float sX[NT][F];
    __shared__ float scale[NT];
    int t = threadIdx.x;
    int nb = blockIdx.x * NT;

    // ---- stage tiles: 1024 4-elem chunks each ----
    #pragma unroll
    for (int it = 0; it < 4; ++it) {
        int i = t + it * 256;
        int n = i >> 5;
        int k4 = (i & 31) << 2;
        ushort4 ua = *(const ushort4*)&aggm[(size_t)(nb + n) * F + k4];
        float4 va; va.x = b2f(ua.x); va.y = b2f(ua.y); va.z = b2f(ua.z); va.w = b2f(ua.w);
        *(float4*)&sA[n][k4] = va;
        float4 vx;
        if constexpr (!CONV2) {
            vx = *(const float4*)&xf[(size_t)(nb + n) * F + k4];
        } else {
            ushort4 ux = *(const ushort4*)&xb[(size_t)(nb + n) * F + k4];
            float4 a4 = *(const float4*)&bn_a[k4];
            float4 b4 = *(const float4*)&bn_b[k4];
            vx.x = fmaf(a4.x, b2f(ux.x), b4.x);
            vx.y = fmaf(a4.y, b2f(ux.y), b4.y);
            vx.z = fmaf(a4.z, b2f(ux.z), b4.z);
            vx.w = fmaf(a4.w, b2f(ux.w), b4.w);
        }
        *(float4*)&sX[n][k4] = vx;
    }
    __syncthreads();

    // ---- dual GEMM with 2-deep weight register double-buffer ----
    int tn = (t >> 5) << 2;   // node base (0..28)
    int to = (t & 31) << 2;   // out base  (0..124)
    float acc[4][4];
    #pragma unroll
    for (int i = 0; i < 4; ++i)
        #pragma unroll
        for (int j = 0; j < 4; ++j) acc[i][j] = 0.f;

    float4 wl[2][4], wr[2][4];
    WLOAD(0, 0)
    for (int k = 0; k < F - 8; k += 8) {
        WLOAD(1, (k + 4))
        KSTEP(0)
        k += 4;
        WLOAD(0, (k + 4))
        KSTEP(1)
        k -= 4;
    }
    {
        int k = F - 8;
        WLOAD(1, (k + 4))
        KSTEP(0)
        k += 4;
        KSTEP(1)
    }

    float4 bv = *(const float4*)&bias[to];
    #pragma unroll
    for (int ni = 0; ni < 4; ++ni) {
        acc[ni][0] += bv.x; acc[ni][1] += bv.y; acc[ni][2] += bv.z; acc[ni][3] += bv.w;
    }

    #pragma unroll
    for (int ni = 0; ni < 4; ++ni) {
        float s = acc[ni][0] * acc[ni][0] + acc[ni][1] * acc[ni][1]
                + acc[ni][2] * acc[ni][2] + acc[ni][3] * acc[ni][3];
        #pragma unroll
        for (int off = 1; off <= 16; off <<= 1) s += __shfl_xor(s, off);
        if ((t & 31) == 0) scale[tn + ni] = 1.f / fmaxf(sqrtf(s), 1e-12f);
    }
    __syncthreads();

    if constexpr (!CONV2) {
        // normalize + relu; f32 copy into sA for exact BN stats, bf16 store to rbh
        #pragma unroll
        for (int ni = 0; ni < 4; ++ni) {
            float sc = scale[tn + ni];
            float4 v;
            v.x = fmaxf(acc[ni][0] * sc, 0.f);
            v.y = fmaxf(acc[ni][1] * sc, 0.f);
            v.z = fmaxf(acc[ni][2] * sc, 0.f);
            v.w = fmaxf(acc[ni][3] * sc, 0.f);
            *(float4*)&sA[tn + ni][to] = v;
            ushort4 o; o.x = f2b(v.x); o.y = f2b(v.y); o.z = f2b(v.z); o.w = f2b(v.w);
            *(ushort4*)&rbh[(size_t)(nb + tn + ni) * F + to] = o;
        }
        __syncthreads();
        if (t < F) {
            float s = 0.f, s2 = 0.f;
            #pragma unroll
            for (int r = 0; r < NT; ++r) {
                float v = sA[r][t];
                s += v; s2 += v * v;
            }
            atomicAdd(&stats[t], s);
            atomicAdd(&stats[F + t], s2);
        }
    } else {
        #pragma unroll
        for (int ni = 0; ni < 4; ++ni) {
            float sc = scale[tn + ni];
            float4 v;
            v.x = acc[ni][0] * sc; v.y = acc[ni][1] * sc;
            v.z = acc[ni][2] * sc; v.w = acc[ni][3] * sc;
            *(float4*)&sA[tn + ni][to] = v;
        }
        __syncthreads();
        for (int p = t; p < NT * NC; p += 256) {
            int n = p >> 4, c = p & 15;
            float s = bfc[c];
            for (int o = 0; o < F; o += 4) {
                float4 h4 = *(const float4*)&sA[n][o];
                float4 w4 = *(const float4*)&Wfc[c * F + o];
                s += h4.x * w4.x + h4.y * w4.y + h4.z * w4.z + h4.w * w4.w;
            }
            out[(size_t)(nb + n) * NC + c] = s;
        }
    }
}

extern "C" void kernel_launch(void* const* d_in, const int* in_sizes, int n_in,
                              void* d_out, int out_size, void* d_ws, size_t ws_size,
                              hipStream_t stream) {
    const float* x     = (const float*)d_in[0];
    const int*   ei    = (const int*)d_in[1];
    const float* W1l   = (const float*)d_in[2];
    const float* b1l   = (const float*)d_in[3];
    const float* W1r   = (const float*)d_in[4];
    const float* gamma = (const float*)d_in[5];
    const float* beta  = (const float*)d_in[6];
    const float* W2l   = (const float*)d_in[7];
    const float* b2l   = (const float*)d_in[8];
    const float* W2r   = (const float*)d_in[9];
    const float* Wfc   = (const float*)d_in[10];
    const float* bfc   = (const float*)d_in[11];

    char* ws = (char*)d_ws;
    int*            rowptr = (int*)(ws + OFF_ROWPTR);
    int*            fill   = (int*)(ws + OFF_FILL);
    int*            bsum   = (int*)(ws + OFF_BSUM);
    int*            sorted = (int*)(ws + OFF_SORTED);
    float*          stats  = (float*)(ws + OFF_STATS);
    float*          WT     = (float*)(ws + OFF_WT);
    unsigned short* rbh    = (unsigned short*)(ws + OFF_RBH);
    unsigned short* aggm   = (unsigned short*)(ws + OFF_AGGM);
    float*          out    = (float*)d_out;

    hipMemsetAsync(fill, 0, NN * sizeof(int), stream);
    hipMemsetAsync(stats, 0, 256 * sizeof(float), stream);

    k_transpose<<<256, 256, 0, stream>>>(W1l, W1r, W2l, W2r, WT);
    k_hist<<<(NE + 255) / 256, 256, 0, stream>>>(ei, fill);
    k_scan1<<<40, 1024, 0, stream>>>(fill, rowptr, bsum);
    k_scan2<<<1, 64, 0, stream>>>(bsum, rowptr);
    k_scan3<<<40, 1024, 0, stream>>>(rowptr, bsum, fill);
    k_scatter<<<(NE + 255) / 256, 256, 0, stream>>>(ei, fill, sorted);

    // conv1
    k_agg<0><<<NN / 4, 256, 0, stream>>>(x, nullptr, rowptr, sorted, nullptr, nullptr, aggm);
    k_gemm<0><<<NN / NT, 256, 0, stream>>>(aggm, x, nullptr, WT, WT + 16384, b1l,
                                           nullptr, nullptr, rbh, stats,
                                           nullptr, nullptr, nullptr);
    k_bnfinal<<<1, 128, 0, stream>>>(stats, gamma, beta);

    // conv2 (+ fused fc)
    k_agg<1><<<NN / 4, 256, 0, stream>>>(nullptr, rbh, rowptr, sorted, stats + 256, stats + 384, aggm);
    k_gemm<1><<<NN / NT, 256, 0, stream>>>(aggm, nullptr, rbh, WT + 32768, WT + 49152, b2l,
                                           stats + 256, stats + 384, nullptr, nullptr,
                                           Wfc, bfc, out);
}